// Round 6
// baseline (735.327 us; speedup 1.0000x reference)
//
#include <hip/hip_runtime.h>
#include <cstdint>
#include <cstddef>

#define MROWS 16384     // B*R = 32*512
#define INDIM 1024
#define DD    256
#define TWO_D 512
#define KC    4096
#define OUTD  1024
#define NZQ   (MROWS * OUTD)   // 16777216

typedef short bfrag __attribute__((ext_vector_type(8)));   // 8 bf16 (4 VGPRs)
typedef float ffrag __attribute__((ext_vector_type(4)));   // 4 fp32 acc

__device__ __forceinline__ ushort f2bf(float f) {          // RNE f32->bf16
    uint u = __float_as_uint(f);
    return (ushort)((u + 0x7FFFu + ((u >> 16) & 1u)) >> 16);
}

// ---------------------------------------------------------------------------
// K1: h = z @ W_qa + b_qa  (fp32, strict sequential-k accumulation -> matches
// np sgemm bits; LOAD-BEARING: per-element FMA chain must stay k-ascending).
// 128x128 tile, 8x8 microtile, double-buffered LDS with register prefetch:
// one barrier per BK=16 tile; global loads for tile t+1 issue before tile t's
// 1024 FMAs, LDS write after compute -> HBM latency hidden at 2 waves/SIMD.
// Grid (128, 4), block 256. Also emits h_bf16.
// ---------------------------------------------------------------------------
__global__ __launch_bounds__(256) void k_gemm1(const float* __restrict__ z,
                                               const float* __restrict__ Wqa,
                                               const float* __restrict__ bqa,
                                               float* __restrict__ h,
                                               ushort* __restrict__ hbf) {
    __shared__ float As[2][16][132];   // [buf][k][row]
    __shared__ float Bs[2][16][132];   // [buf][k][col]
    const int tid = threadIdx.x;
    const int tx = tid & 15, ty = tid >> 4;
    const int rb = blockIdx.x * 128;
    const int cb = blockIdx.y * 128;

    // staging coords
    const int ar = tid >> 1;          // 0..127 (A row)
    const int ak = (tid & 1) * 8;     // 0 / 8  (A k-sub)
    const int br = tid >> 4;          // 0..15  (B k-row)
    const int bc = (tid & 15) * 4;    // 0..60  (B col-sub; +64 for 2nd half)

    const float* aptr = &z[(size_t)(rb + ar) * INDIM + ak];
    const float* bptr = &Wqa[(size_t)br * TWO_D + cb + bc];

    float acc[8][8] = {};

    {   // stage tile 0 into buf 0
        float4 a0 = *reinterpret_cast<const float4*>(aptr);
        float4 a1 = *reinterpret_cast<const float4*>(aptr + 4);
        As[0][ak + 0][ar] = a0.x; As[0][ak + 1][ar] = a0.y;
        As[0][ak + 2][ar] = a0.z; As[0][ak + 3][ar] = a0.w;
        As[0][ak + 4][ar] = a1.x; As[0][ak + 5][ar] = a1.y;
        As[0][ak + 6][ar] = a1.z; As[0][ak + 7][ar] = a1.w;
        *reinterpret_cast<float4*>(&Bs[0][br][bc]) =
            *reinterpret_cast<const float4*>(bptr);
        *reinterpret_cast<float4*>(&Bs[0][br][bc + 64]) =
            *reinterpret_cast<const float4*>(bptr + 64);
    }
    __syncthreads();

    for (int t = 0; t < 64; ++t) {         // 64 BK=16 tiles
        const int cur = t & 1;
        float4 pa0, pa1, pb0, pb1;
        if (t < 63) {                       // issue prefetch before compute
            const float* an = aptr + (t + 1) * 16;
            const float* bn = bptr + (size_t)(t + 1) * 16 * TWO_D;
            pa0 = *reinterpret_cast<const float4*>(an);
            pa1 = *reinterpret_cast<const float4*>(an + 4);
            pb0 = *reinterpret_cast<const float4*>(bn);
            pb1 = *reinterpret_cast<const float4*>(bn + 64);
        }
        #pragma unroll
        for (int kk = 0; kk < 16; ++kk) {   // k strictly ascending
            float4 x0 = *reinterpret_cast<const float4*>(&As[cur][kk][ty * 4]);
            float4 x1 = *reinterpret_cast<const float4*>(&As[cur][kk][64 + ty * 4]);
            float4 y0 = *reinterpret_cast<const float4*>(&Bs[cur][kk][tx * 4]);
            float4 y1 = *reinterpret_cast<const float4*>(&Bs[cur][kk][64 + tx * 4]);
            float av[8] = {x0.x, x0.y, x0.z, x0.w, x1.x, x1.y, x1.z, x1.w};
            float bv[8] = {y0.x, y0.y, y0.z, y0.w, y1.x, y1.y, y1.z, y1.w};
            #pragma unroll
            for (int i = 0; i < 8; ++i)
                #pragma unroll
                for (int j = 0; j < 8; ++j)
                    acc[i][j] = fmaf(av[i], bv[j], acc[i][j]);
        }
        if (t < 63) {                       // write prefetched tile to other buf
            const int nxt = cur ^ 1;
            As[nxt][ak + 0][ar] = pa0.x; As[nxt][ak + 1][ar] = pa0.y;
            As[nxt][ak + 2][ar] = pa0.z; As[nxt][ak + 3][ar] = pa0.w;
            As[nxt][ak + 4][ar] = pa1.x; As[nxt][ak + 5][ar] = pa1.y;
            As[nxt][ak + 6][ar] = pa1.z; As[nxt][ak + 7][ar] = pa1.w;
            *reinterpret_cast<float4*>(&Bs[nxt][br][bc])      = pb0;
            *reinterpret_cast<float4*>(&Bs[nxt][br][bc + 64]) = pb1;
        }
        __syncthreads();                    // single barrier per tile
    }

    #pragma unroll
    for (int i = 0; i < 8; ++i) {
        const int row = rb + ((i < 4) ? (ty * 4 + i) : (64 + ty * 4 + i - 4));
        #pragma unroll
        for (int jh = 0; jh < 2; ++jh) {
            const int col = cb + jh * 64 + tx * 4;
            float v0 = acc[i][jh * 4 + 0] + bqa[col + 0];
            float v1 = acc[i][jh * 4 + 1] + bqa[col + 1];
            float v2 = acc[i][jh * 4 + 2] + bqa[col + 2];
            float v3 = acc[i][jh * 4 + 3] + bqa[col + 3];
            float4 vf = {v0, v1, v2, v3};
            *reinterpret_cast<float4*>(&h[(size_t)row * TWO_D + col]) = vf;
            ushort u[4] = {f2bf(v0), f2bf(v1), f2bf(v2), f2bf(v3)};
            *reinterpret_cast<uint2*>(&hbf[(size_t)row * TWO_D + col]) =
                *reinterpret_cast<uint2*>(u);
        }
    }
}

// ---------------------------------------------------------------------------
// K2: fused prep. Blocks [0,8192): row norms R[half][row] (fp32, few-ulp
// accuracy suffices — uniform grid shift preserves argmin/ties).
// Blocks [8192,10240): emb1|emb2 -> bf16. Blocks [10240,10752): W_pq -> bf16^T.
// ---------------------------------------------------------------------------
__global__ __launch_bounds__(256) void k_prep(const float* __restrict__ h,
                                              const float* __restrict__ e1,
                                              const float* __restrict__ e2,
                                              const float* __restrict__ Wpq,
                                              float* __restrict__ Rn,
                                              ushort* __restrict__ ebf,
                                              ushort* __restrict__ wbfT) {
    const int b = blockIdx.x;
    if (b < 8192) {
        const int wave = threadIdx.x >> 6;
        const int lane = threadIdx.x & 63;
        const int item = b * 4 + wave;
        const int row  = item & (MROWS - 1);
        const int half = item >> 14;
        float4 v = *reinterpret_cast<const float4*>(&h[(size_t)row * TWO_D + half * DD + lane * 4]);
        float s = v.x * v.x + v.y * v.y + v.z * v.z + v.w * v.w;
        #pragma unroll
        for (int off = 32; off; off >>= 1) s += __shfl_down(s, off, 64);
        if (lane == 0) Rn[half * MROWS + row] = s;
    } else if (b < 10240) {
        const size_t v = ((size_t)(b - 8192) * 256 + threadIdx.x) * 4;
        const size_t half = (size_t)KC * DD;
        const float* src = (v < half) ? (e1 + v) : (e2 + (v - half));
        float4 f = *reinterpret_cast<const float4*>(src);
        ebf[v + 0] = f2bf(f.x); ebf[v + 1] = f2bf(f.y);
        ebf[v + 2] = f2bf(f.z); ebf[v + 3] = f2bf(f.w);
    } else {
        const int e = ((b - 10240) * 256 + threadIdx.x) * 4;   // 0..524284
        const int k = e >> 10, c = e & 1023;
        float4 f = *reinterpret_cast<const float4*>(&Wpq[e]);
        wbfT[(size_t)(c + 0) * TWO_D + k] = f2bf(f.x);
        wbfT[(size_t)(c + 1) * TWO_D + k] = f2bf(f.y);
        wbfT[(size_t)(c + 2) * TWO_D + k] = f2bf(f.z);
        wbfT[(size_t)(c + 3) * TWO_D + k] = f2bf(f.w);
    }
}

// ---------------------------------------------------------------------------
// K3: MFMA score pass (selection only). C[row,code] = <h_bf, e_bf>, bf16
// 16x16x32 MFMA, 128x128 block tile, wave = 64x64 (4x4 frags), K=256 in 8
// chunks of 32. XOR-swizzled LDS -> conflict-free frag reads. Per-wave
// per-row top-2 packed keys -> cand[cb][seg(64)][row][2]. Grid (128,32,2).
// ---------------------------------------------------------------------------
__global__ __launch_bounds__(256) void k_score_mfma(const ushort* __restrict__ hbf,
                                                    const ushort* __restrict__ ebf,
                                                    uint* __restrict__ cand) {
    __shared__ ushort Ab[4][128][8];   // 8 KB
    __shared__ ushort Bb[4][128][8];   // 8 KB
    const int tid = threadIdx.x;
    const int l = tid & 63, w = tid >> 6;
    const int rb    = blockIdx.x * 128;
    const int cbcol = blockIdx.y * 128;
    const int cbk   = blockIdx.z;
    const ushort* hb = hbf + cbk * DD;                 // row stride TWO_D
    const ushort* eb = ebf + (size_t)cbk * KC * DD;    // row stride DD

    const int ry = (w & 1) * 64;
    const int cy = (w >> 1) * 64;

    ffrag acc[4][4];
    #pragma unroll
    for (int i = 0; i < 4; ++i)
        #pragma unroll
        for (int j = 0; j < 4; ++j)
            acc[i][j] = (ffrag){0.f, 0.f, 0.f, 0.f};

    for (int k0 = 0; k0 < DD; k0 += 32) {
        #pragma unroll
        for (int it = 0; it < 2; ++it) {
            const int r = it * 64 + l;
            uint4 va = *reinterpret_cast<const uint4*>(hb + (size_t)(rb + r) * TWO_D + k0 + w * 8);
            *reinterpret_cast<uint4*>(&Ab[w ^ ((r >> 1) & 3)][r][0]) = va;
            uint4 vb = *reinterpret_cast<const uint4*>(eb + (size_t)(cbcol + r) * DD + k0 + w * 8);
            *reinterpret_cast<uint4*>(&Bb[w ^ ((r >> 1) & 3)][r][0]) = vb;
        }
        __syncthreads();
        const int q = l >> 4, li = l & 15;
        bfrag afr[4], bfr[4];
        #pragma unroll
        for (int rf = 0; rf < 4; ++rf) {
            const int r = ry + rf * 16 + li;
            afr[rf] = *reinterpret_cast<const bfrag*>(&Ab[q ^ ((r >> 1) & 3)][r][0]);
        }
        #pragma unroll
        for (int cf = 0; cf < 4; ++cf) {
            const int c = cy + cf * 16 + li;
            bfr[cf] = *reinterpret_cast<const bfrag*>(&Bb[q ^ ((c >> 1) & 3)][c][0]);
        }
        #pragma unroll
        for (int rf = 0; rf < 4; ++rf)
            #pragma unroll
            for (int cf = 0; cf < 4; ++cf)
                acc[rf][cf] = __builtin_amdgcn_mfma_f32_16x16x32_bf16(afr[rf], bfr[cf],
                                                                      acc[rf][cf], 0, 0, 0);
        __syncthreads();
    }

    const int q = l >> 4, li = l & 15;
    const int seg = blockIdx.y * 2 + (w >> 1);
    #pragma unroll
    for (int rf = 0; rf < 4; ++rf) {
        #pragma unroll
        for (int reg = 0; reg < 4; ++reg) {
            const int row = rb + ry + rf * 16 + q * 4 + reg;
            uint k1 = 0, k2 = 0;
            #pragma unroll
            for (int cf = 0; cf < 4; ++cf) {
                float v = acc[rf][cf][reg];
                const int code = cbcol + cy + cf * 16 + li;
                uint u = __float_as_uint(v);
                u ^= (0x80000000u | (uint)((int)u >> 31));      // order-preserving flip
                const uint key = (u & 0xFFFFF000u) | (uint)code;
                if (key > k1) { k2 = k1; k1 = key; }
                else if (key > k2) { k2 = key; }
            }
            #pragma unroll
            for (int m = 1; m < 16; m <<= 1) {
                uint o1 = __shfl_xor((int)k1, m, 64);
                uint o2 = __shfl_xor((int)k2, m, 64);
                uint n1 = k1 > o1 ? k1 : o1;
                uint lo = k1 > o1 ? o1 : k1;
                uint hi2 = k2 > o2 ? k2 : o2;
                k2 = lo > hi2 ? lo : hi2;
                k1 = n1;
            }
            if (li == 0) {
                const size_t base = ((size_t)(cbk * 64 + seg) * MROWS + row) * 2;
                cand[base] = k1; cand[base + 1] = k2;
            }
        }
    }
}

// ---------------------------------------------------------------------------
// K4: fused reduce + loss. One wave per row: for each codebook, scan 64 segs
// x top-2 keys -> top-8, exact fp32 sequential dot (np-sgemm bits),
// d = fp32(Rn - 2M), min(d, idx); then 64-lane squared-diff loss reduction.
// Grid 4096, block 256 (4 rows/block).
// ---------------------------------------------------------------------------
__global__ __launch_bounds__(256) void k_reduce_loss(const uint* __restrict__ cand,
                                                     const float* __restrict__ h,
                                                     const float* __restrict__ emb1,
                                                     const float* __restrict__ emb2,
                                                     const float* __restrict__ Rn,
                                                     float* __restrict__ dout_idx,
                                                     float* __restrict__ dout_loss) {
    const int tid = threadIdx.x;
    const int l = tid & 63, w = tid >> 6;
    const int row = blockIdx.x * 4 + w;

    int win[2];
    #pragma unroll
    for (int cb = 0; cb < 2; ++cb) {
        const size_t base = ((size_t)(cb * 64 + l) * MROWS + row) * 2;
        uint k1 = cand[base], k2 = cand[base + 1];
        uint mykey = 0;
        #pragma unroll
        for (int t = 0; t < 8; ++t) {
            uint m = k1 > k2 ? k1 : k2;
            #pragma unroll
            for (int off = 1; off < 64; off <<= 1) {
                uint o = __shfl_xor((int)m, off, 64);
                m = m > o ? m : o;
            }
            if (k1 == m) k1 = 0; else if (k2 == m) k2 = 0;
            if (l == t) mykey = m;
        }
        float dd = INFINITY; int code = 0x7fffffff;
        if (l < 8) {
            code = (int)(mykey & 0xFFFu);
            const float* hr = h + (size_t)row * TWO_D + cb * DD;
            const float* er = (cb ? emb2 : emb1) + (size_t)code * DD;
            float M = 0.f;
            for (int d = 0; d < DD; ++d) M = fmaf(hr[d], er[d], M);  // sequential chain
            dd = Rn[cb * MROWS + row] - 2.0f * M;    // literal fp32, as np
        }
        #pragma unroll
        for (int off = 1; off < 8; off <<= 1) {
            float od = __shfl_xor(dd, off, 64);
            int   oc = __shfl_xor(code, off, 64);
            if (od < dd || (od == dd && oc < code)) { dd = od; code = oc; }
        }
        win[cb] = __shfl(code, 0, 64);
    }

    // fused loss: each lane covers 4 dims of each half
    const float* hr = h + (size_t)row * TWO_D;
    float4 h1 = *reinterpret_cast<const float4*>(hr + l * 4);
    float4 h2 = *reinterpret_cast<const float4*>(hr + DD + l * 4);
    float4 q1 = *reinterpret_cast<const float4*>(emb1 + (size_t)win[0] * DD + l * 4);
    float4 q2 = *reinterpret_cast<const float4*>(emb2 + (size_t)win[1] * DD + l * 4);
    float a0 = q1.x - h1.x, a1 = q1.y - h1.y, a2 = q1.z - h1.z, a3 = q1.w - h1.w;
    float b0 = q2.x - h2.x, b1 = q2.y - h2.y, b2 = q2.z - h2.z, b3 = q2.w - h2.w;
    float p = a0*a0 + a1*a1 + a2*a2 + a3*a3 + b0*b0 + b1*b1 + b2*b2 + b3*b3;
    #pragma unroll
    for (int off = 32; off; off >>= 1) p += __shfl_down(p, off, 64);
    if (l == 0) {
        dout_idx[row]         = (float)win[0];
        dout_idx[MROWS + row] = (float)win[1];
        dout_loss[row]        = p * (0.625f / 256.0f);
    }
}

// ---------------------------------------------------------------------------
// K5: out = gather(e_bf, idx) @ W_pq_bf + b_pq via MFMA (bf16 in, fp32 out).
// Grid (128, 8), block 256.
// ---------------------------------------------------------------------------
__global__ __launch_bounds__(256) void k_gemm2m(const ushort* __restrict__ ebf,
                                                const ushort* __restrict__ wbfT,
                                                const float* __restrict__ idxf,
                                                const float* __restrict__ bpq,
                                                float* __restrict__ out) {
    __shared__ ushort Ab[4][128][8];
    __shared__ ushort Bb[4][128][8];
    const int tid = threadIdx.x;
    const int l = tid & 63, w = tid >> 6;
    const int rb    = blockIdx.x * 128;
    const int cbcol = blockIdx.y * 128;
    const int ry = (w & 1) * 64;
    const int cy = (w >> 1) * 64;
    const ushort* e1 = ebf;
    const ushort* e2 = ebf + (size_t)KC * DD;

    int ia[2], ib[2];
    ia[0] = (int)idxf[rb + l];            ia[1] = (int)idxf[rb + 64 + l];
    ib[0] = (int)idxf[MROWS + rb + l];    ib[1] = (int)idxf[MROWS + rb + 64 + l];

    ffrag acc[4][4];
    #pragma unroll
    for (int i = 0; i < 4; ++i)
        #pragma unroll
        for (int j = 0; j < 4; ++j)
            acc[i][j] = (ffrag){0.f, 0.f, 0.f, 0.f};

    for (int k0 = 0; k0 < TWO_D; k0 += 32) {
        const int cbs = k0 >> 8;
        const int kk  = (k0 & 255) + w * 8;
        #pragma unroll
        for (int it = 0; it < 2; ++it) {
            const int r = it * 64 + l;
            const int idx = cbs ? ib[it] : ia[it];
            const ushort* src = (cbs ? e2 : e1) + (size_t)idx * DD + kk;
            *reinterpret_cast<uint4*>(&Ab[w ^ ((r >> 1) & 3)][r][0]) =
                *reinterpret_cast<const uint4*>(src);
            const ushort* bs = wbfT + (size_t)(cbcol + r) * TWO_D + k0 + w * 8;
            *reinterpret_cast<uint4*>(&Bb[w ^ ((r >> 1) & 3)][r][0]) =
                *reinterpret_cast<const uint4*>(bs);
        }
        __syncthreads();
        const int q = l >> 4, li = l & 15;
        bfrag afr[4], bfr[4];
        #pragma unroll
        for (int rf = 0; rf < 4; ++rf) {
            const int r = ry + rf * 16 + li;
            afr[rf] = *reinterpret_cast<const bfrag*>(&Ab[q ^ ((r >> 1) & 3)][r][0]);
        }
        #pragma unroll
        for (int cf = 0; cf < 4; ++cf) {
            const int c = cy + cf * 16 + li;
            bfr[cf] = *reinterpret_cast<const bfrag*>(&Bb[q ^ ((c >> 1) & 3)][c][0]);
        }
        #pragma unroll
        for (int rf = 0; rf < 4; ++rf)
            #pragma unroll
            for (int cf = 0; cf < 4; ++cf)
                acc[rf][cf] = __builtin_amdgcn_mfma_f32_16x16x32_bf16(afr[rf], bfr[cf],
                                                                      acc[rf][cf], 0, 0, 0);
        __syncthreads();
    }

    const int q = l >> 4, li = l & 15;
    #pragma unroll
    for (int rf = 0; rf < 4; ++rf) {
        #pragma unroll
        for (int reg = 0; reg < 4; ++reg) {
            const int row = rb + ry + rf * 16 + q * 4 + reg;
            #pragma unroll
            for (int cf = 0; cf < 4; ++cf) {
                const int col = cbcol + cy + cf * 16 + li;
                out[(size_t)row * OUTD + col] = acc[rf][cf][reg] + bpq[col];
            }
        }
    }
}

// ---------------------------------------------------------------------------
extern "C" void kernel_launch(void* const* d_in, const int* in_sizes, int n_in,
                              void* d_out, int out_size, void* d_ws, size_t ws_size,
                              hipStream_t stream) {
    const float* z    = (const float*)d_in[0];
    const float* Wqa  = (const float*)d_in[1];
    const float* bqa  = (const float*)d_in[2];
    const float* emb1 = (const float*)d_in[3];
    const float* emb2 = (const float*)d_in[4];
    const float* Wpq  = (const float*)d_in[5];
    const float* bpq  = (const float*)d_in[6];
    float* out = (float*)d_out;

    const size_t H = (size_t)MROWS * TWO_D;        // 8,388,608
    float*  hbuf = (float*)d_ws;                   // [H]            33.55 MB
    float*  Rn   = hbuf + H;                       // [2*MROWS]       0.13 MB
    ushort* hbf  = (ushort*)(Rn + 2 * MROWS);      // [H]            16.78 MB
    ushort* ebf  = hbf + H;                        // [2*KC*DD]       4.19 MB
    ushort* wbfT = ebf + 2 * (size_t)KC * DD;      // [OUTD*TWO_D]    1.05 MB
    uint*   cand = (uint*)(wbfT + (size_t)OUTD * TWO_D); // [2*64*MROWS*2] 16.78 MB

    float* dout_idx  = out + NZQ;
    float* dout_loss = out + NZQ + 2 * MROWS;

    k_gemm1<<<dim3(128, 4), 256, 0, stream>>>(z, Wqa, bqa, hbuf, hbf);
    k_prep<<<10752, 256, 0, stream>>>(hbuf, emb1, emb2, Wpq, Rn, ebf, wbfT);
    k_score_mfma<<<dim3(128, 32, 2), 256, 0, stream>>>(hbf, ebf, cand);
    k_reduce_loss<<<4096, 256, 0, stream>>>(cand, hbuf, emb1, emb2, Rn,
                                            dout_idx, dout_loss);
    k_gemm2m<<<dim3(128, 8), 256, 0, stream>>>(ebf, wbfT, dout_idx, bpq, out);
}